// Round 1
// baseline (1614.106 us; speedup 1.0000x reference)
//
#include <hip/hip_runtime.h>
#include <hip/hip_bf16.h>
#include <cstdint>
#include <cstddef>

#define T_TOK 4096
#define DMODEL 2048
#define DFF 8192
#define NEXP 8
#define NPAIR (T_TOK * 2)   // each token picks exactly 2 distinct experts

typedef __bf16 bf16_t;
typedef __bf16 bf16x8 __attribute__((ext_vector_type(8)));
typedef float fx4 __attribute__((ext_vector_type(4)));

// ---------------- router: softmax over 8, top-2, renormalize, compact per expert ----------------
__global__ void router_kernel(const float* __restrict__ gating, int* __restrict__ counts,
                              int* __restrict__ tok_list, float* __restrict__ w_list) {
    int t = blockIdx.x * blockDim.x + threadIdx.x;
    if (t >= T_TOK) return;
    float l[NEXP];
    float mx = -1e30f;
#pragma unroll
    for (int e = 0; e < NEXP; e++) { l[e] = gating[t * NEXP + e]; mx = fmaxf(mx, l[e]); }
#pragma unroll
    for (int e = 0; e < NEXP; e++) { l[e] = __expf(l[e] - mx); }
    // top-2 on exp values (monotonic in logits); ties -> lower index first, like lax.top_k
    int e0 = 0; float p0 = l[0];
#pragma unroll
    for (int e = 1; e < NEXP; e++) { if (l[e] > p0) { p0 = l[e]; e0 = e; } }
    int e1 = -1; float p1 = -1.0f;
#pragma unroll
    for (int e = 0; e < NEXP; e++) { if (e != e0 && l[e] > p1) { p1 = l[e]; e1 = e; } }
    float inv = 1.0f / (p0 + p1);
    float w0 = p0 * inv, w1 = p1 * inv;
    int s0 = atomicAdd(&counts[e0], 1);
    tok_list[e0 * T_TOK + s0] = t; w_list[e0 * T_TOK + s0] = w0;
    int s1 = atomicAdd(&counts[e1], 1);
    tok_list[e1 * T_TOK + s1] = t; w_list[e1 * T_TOK + s1] = w1;
}

__global__ void scan_kernel(const int* __restrict__ counts, int* __restrict__ offsets) {
    if (threadIdx.x == 0 && blockIdx.x == 0) {
        int acc = 0;
        for (int e = 0; e < NEXP; e++) { offsets[e] = acc; acc += counts[e]; }
        offsets[NEXP] = acc;
    }
}

// ---------------- x fp32 -> bf16 ----------------
__global__ void cvt_x_kernel(const float* __restrict__ x, bf16_t* __restrict__ xb) {
    int i = blockIdx.x * blockDim.x + threadIdx.x;   // one thread = 8 elements
    const fx4* src = (const fx4*)x;
    fx4 v0 = src[2 * i], v1 = src[2 * i + 1];
    bf16x8 o;
    o[0] = (bf16_t)v0[0]; o[1] = (bf16_t)v0[1]; o[2] = (bf16_t)v0[2]; o[3] = (bf16_t)v0[3];
    o[4] = (bf16_t)v1[0]; o[5] = (bf16_t)v1[1]; o[6] = (bf16_t)v1[2]; o[7] = (bf16_t)v1[3];
    *(bf16x8*)(xb + (size_t)i * 8) = o;
}

// ---------------- gate_up GEMM: h = silu(x Wg^T) * (x Wu^T), bf16 out ----------------
// tile 128x128x64, 4 waves (2x2), each wave 64x64 per matrix, dual accumulators (g,u)
#define BM 128
#define BN 128
#define BK 64

__global__ __launch_bounds__(256, 2) void gateup_kernel(
    const bf16_t* __restrict__ xb, const float* __restrict__ gup,
    const int* __restrict__ counts, const int* __restrict__ offsets,
    const int* __restrict__ tok_list, bf16_t* __restrict__ h_buf)
{
    const int e = blockIdx.z;
    const int cnt = counts[e];
    const int mbase = blockIdx.y * BM;
    if (mbase >= cnt) return;
    const int nbase = blockIdx.x * BN;
    const int off_e = offsets[e];

    __shared__ bf16_t lds_a[BM * BK];
    __shared__ bf16_t lds_g[BN * BK];
    __shared__ bf16_t lds_u[BN * BK];

    const int tid = threadIdx.x;
    const int lane = tid & 63;
    const int w = tid >> 6;
    const int wm = (w >> 1) * 64, wn = (w & 1) * 64;

    // staging assignment: 1024 16B-chunks per tile, 4 per thread. chunk=(row, c) c in [0,8)
    const bf16_t* a_src[4];
    const float* g_src[4];
    const float* u_src[4];
    int st_lds[4];
    const float* gbase = gup + (size_t)e * (2 * DFF) * DMODEL;
#pragma unroll
    for (int t = 0; t < 4; t++) {
        int cid = t * 256 + tid;
        int row = cid >> 3, c = cid & 7;
        int slot = mbase + row;
        int tok = (slot < cnt) ? tok_list[e * T_TOK + slot] : 0;
        a_src[t] = xb + (size_t)tok * DMODEL + c * 8;
        g_src[t] = gbase + (size_t)(nbase + row) * DMODEL + c * 8;
        u_src[t] = gbase + (size_t)(DFF + nbase + row) * DMODEL + c * 8;
        st_lds[t] = row * BK + ((c ^ (row & 7)) * 8);   // XOR-swizzled, element index
    }

    fx4 accg[4][4] = {};
    fx4 accu[4][4] = {};

    for (int k0 = 0; k0 < DMODEL; k0 += BK) {
#pragma unroll
        for (int t = 0; t < 4; t++) {
            *(uint4*)(&lds_a[st_lds[t]]) = *(const uint4*)(a_src[t] + k0);
            fx4 v0 = *(const fx4*)(g_src[t] + k0);
            fx4 v1 = *(const fx4*)(g_src[t] + k0 + 4);
            bf16x8 bg;
            bg[0] = (bf16_t)v0[0]; bg[1] = (bf16_t)v0[1]; bg[2] = (bf16_t)v0[2]; bg[3] = (bf16_t)v0[3];
            bg[4] = (bf16_t)v1[0]; bg[5] = (bf16_t)v1[1]; bg[6] = (bf16_t)v1[2]; bg[7] = (bf16_t)v1[3];
            *(bf16x8*)(&lds_g[st_lds[t]]) = bg;
            fx4 q0 = *(const fx4*)(u_src[t] + k0);
            fx4 q1 = *(const fx4*)(u_src[t] + k0 + 4);
            bf16x8 bu;
            bu[0] = (bf16_t)q0[0]; bu[1] = (bf16_t)q0[1]; bu[2] = (bf16_t)q0[2]; bu[3] = (bf16_t)q0[3];
            bu[4] = (bf16_t)q1[0]; bu[5] = (bf16_t)q1[1]; bu[6] = (bf16_t)q1[2]; bu[7] = (bf16_t)q1[3];
            *(bf16x8*)(&lds_u[st_lds[t]]) = bu;
        }
        __syncthreads();
#pragma unroll
        for (int kp = 0; kp < 2; kp++) {
            bf16x8 af[4], bfr[4];
            const int ke = kp * 4 + (lane >> 4);
#pragma unroll
            for (int m = 0; m < 4; m++) {
                int row = wm + m * 16 + (lane & 15);
                af[m] = *(const bf16x8*)(&lds_a[row * BK + ((ke ^ (row & 7)) * 8)]);
            }
#pragma unroll
            for (int n = 0; n < 4; n++) {
                int row = wn + n * 16 + (lane & 15);
                bfr[n] = *(const bf16x8*)(&lds_g[row * BK + ((ke ^ (row & 7)) * 8)]);
            }
#pragma unroll
            for (int m = 0; m < 4; m++)
#pragma unroll
                for (int n = 0; n < 4; n++)
                    accg[m][n] = __builtin_amdgcn_mfma_f32_16x16x32_bf16(af[m], bfr[n], accg[m][n], 0, 0, 0);
#pragma unroll
            for (int n = 0; n < 4; n++) {
                int row = wn + n * 16 + (lane & 15);
                bfr[n] = *(const bf16x8*)(&lds_u[row * BK + ((ke ^ (row & 7)) * 8)]);
            }
#pragma unroll
            for (int m = 0; m < 4; m++)
#pragma unroll
                for (int n = 0; n < 4; n++)
                    accu[m][n] = __builtin_amdgcn_mfma_f32_16x16x32_bf16(af[m], bfr[n], accu[m][n], 0, 0, 0);
        }
        __syncthreads();
    }

    // epilogue: h = silu(g) * u  -> bf16
    const int colbase = nbase + wn + (lane & 15);
#pragma unroll
    for (int m = 0; m < 4; m++) {
        int rbase = wm + m * 16 + ((lane >> 4) * 4);
#pragma unroll
        for (int j = 0; j < 4; j++) {
            int slot = mbase + rbase + j;
            if (slot < cnt) {
                size_t hrow = (size_t)(off_e + slot);
#pragma unroll
                for (int n = 0; n < 4; n++) {
                    float g = accg[m][n][j];
                    float u = accu[m][n][j];
                    float hv = g * u / (1.0f + __expf(-g));
                    h_buf[hrow * DFF + colbase + n * 16] = (bf16_t)hv;
                }
            }
        }
    }
}

// ---------------- down GEMM: out[tok] += w * (h Wd^T) ----------------
__global__ __launch_bounds__(256, 2) void down_kernel(
    const bf16_t* __restrict__ h_buf, const float* __restrict__ dwn,
    const int* __restrict__ counts, const int* __restrict__ offsets,
    const int* __restrict__ tok_list, const float* __restrict__ w_list,
    float* __restrict__ out)
{
    const int e = blockIdx.z;
    const int cnt = counts[e];
    const int mbase = blockIdx.y * BM;
    if (mbase >= cnt) return;
    const int nbase = blockIdx.x * BN;
    const int off_e = offsets[e];

    __shared__ bf16_t lds_a[BM * BK];
    __shared__ bf16_t lds_b[BN * BK];

    const int tid = threadIdx.x;
    const int lane = tid & 63;
    const int w = tid >> 6;
    const int wm = (w >> 1) * 64, wn = (w & 1) * 64;

    const bf16_t* a_src[4];
    const float* b_src[4];
    int st_lds[4];
    const float* bbase = dwn + (size_t)e * DMODEL * DFF;
#pragma unroll
    for (int t = 0; t < 4; t++) {
        int cid = t * 256 + tid;
        int row = cid >> 3, c = cid & 7;
        int hrow = off_e + mbase + row;
        if (hrow > NPAIR - 1) hrow = NPAIR - 1;
        a_src[t] = h_buf + (size_t)hrow * DFF + c * 8;
        b_src[t] = bbase + (size_t)(nbase + row) * DFF + c * 8;
        st_lds[t] = row * BK + ((c ^ (row & 7)) * 8);
    }

    fx4 acc[4][4] = {};

    for (int k0 = 0; k0 < DFF; k0 += BK) {
#pragma unroll
        for (int t = 0; t < 4; t++) {
            *(uint4*)(&lds_a[st_lds[t]]) = *(const uint4*)(a_src[t] + k0);
            fx4 v0 = *(const fx4*)(b_src[t] + k0);
            fx4 v1 = *(const fx4*)(b_src[t] + k0 + 4);
            bf16x8 bb;
            bb[0] = (bf16_t)v0[0]; bb[1] = (bf16_t)v0[1]; bb[2] = (bf16_t)v0[2]; bb[3] = (bf16_t)v0[3];
            bb[4] = (bf16_t)v1[0]; bb[5] = (bf16_t)v1[1]; bb[6] = (bf16_t)v1[2]; bb[7] = (bf16_t)v1[3];
            *(bf16x8*)(&lds_b[st_lds[t]]) = bb;
        }
        __syncthreads();
#pragma unroll
        for (int kp = 0; kp < 2; kp++) {
            bf16x8 af[4], bfr[4];
            const int ke = kp * 4 + (lane >> 4);
#pragma unroll
            for (int m = 0; m < 4; m++) {
                int row = wm + m * 16 + (lane & 15);
                af[m] = *(const bf16x8*)(&lds_a[row * BK + ((ke ^ (row & 7)) * 8)]);
            }
#pragma unroll
            for (int n = 0; n < 4; n++) {
                int row = wn + n * 16 + (lane & 15);
                bfr[n] = *(const bf16x8*)(&lds_b[row * BK + ((ke ^ (row & 7)) * 8)]);
            }
#pragma unroll
            for (int m = 0; m < 4; m++)
#pragma unroll
                for (int n = 0; n < 4; n++)
                    acc[m][n] = __builtin_amdgcn_mfma_f32_16x16x32_bf16(af[m], bfr[n], acc[m][n], 0, 0, 0);
        }
        __syncthreads();
    }

    const int colbase = nbase + wn + (lane & 15);
#pragma unroll
    for (int m = 0; m < 4; m++) {
        int rbase = wm + m * 16 + ((lane >> 4) * 4);
#pragma unroll
        for (int j = 0; j < 4; j++) {
            int slot = mbase + rbase + j;
            if (slot < cnt) {
                int tok = tok_list[e * T_TOK + slot];
                float wgt = w_list[e * T_TOK + slot];
#pragma unroll
                for (int n = 0; n < 4; n++) {
                    atomicAdd(&out[(size_t)tok * DMODEL + colbase + n * 16], wgt * acc[m][n][j]);
                }
            }
        }
    }
}

// ---------------- launch ----------------
extern "C" void kernel_launch(void* const* d_in, const int* in_sizes, int n_in,
                              void* d_out, int out_size, void* d_ws, size_t ws_size,
                              hipStream_t stream) {
    const float* x      = (const float*)d_in[0];
    const float* gating = (const float*)d_in[1];
    const float* gup    = (const float*)d_in[2];
    const float* dwn    = (const float*)d_in[3];
    float* out = (float*)d_out;

    char* ws = (char*)d_ws;
    int*    counts   = (int*)(ws + 0);          // 8 ints
    int*    offsets  = (int*)(ws + 64);         // 9 ints
    int*    tok_list = (int*)(ws + 128);        // 8*4096 ints  = 128 KB
    float*  w_list   = (float*)(ws + 128 + 131072);             // 128 KB
    bf16_t* xb       = (bf16_t*)(ws + 262400);                  // 16 MB, 256-aligned
    bf16_t* h_buf    = (bf16_t*)(ws + 17039872);                // 134 MB, 256-aligned

    hipMemsetAsync(counts, 0, 64, stream);
    hipMemsetAsync(out, 0, (size_t)out_size * sizeof(float), stream);

    router_kernel<<<dim3(T_TOK / 256), dim3(256), 0, stream>>>(gating, counts, tok_list, w_list);
    scan_kernel<<<dim3(1), dim3(64), 0, stream>>>(counts, offsets);
    cvt_x_kernel<<<dim3(T_TOK * DMODEL / 8 / 256), dim3(256), 0, stream>>>(x, xb);

    gateup_kernel<<<dim3(DFF / BN, T_TOK / BM, NEXP), dim3(256), 0, stream>>>(
        xb, gup, counts, offsets, tok_list, h_buf);

    down_kernel<<<dim3(DMODEL / BN, T_TOK / BM, NEXP), dim3(256), 0, stream>>>(
        h_buf, dwn, counts, offsets, tok_list, w_list, out);
}

// Round 2
// 1599.354 us; speedup vs baseline: 1.0092x; 1.0092x over previous
//
#include <hip/hip_runtime.h>
#include <hip/hip_bf16.h>
#include <cstdint>
#include <cstddef>

#define T_TOK 4096
#define DMODEL 2048
#define DFF 8192
#define NEXP 8
#define NPAIR (T_TOK * 2)   // each token picks exactly 2 distinct experts -> total pairs == 8192 always

typedef __bf16 bf16_t;
typedef __bf16 bf16x8 __attribute__((ext_vector_type(8)));
typedef float fx4 __attribute__((ext_vector_type(4)));

__device__ __forceinline__ void gload16(const bf16_t* src, bf16_t* dst) {
    // width-16 global->LDS direct: dest = (wave-uniform base) + lane*16, source per-lane
    __builtin_amdgcn_global_load_lds(
        (const __attribute__((address_space(1))) uint32_t*)(src),
        (__attribute__((address_space(3))) uint32_t*)(dst), 16, 0, 0);
}

__device__ __forceinline__ bf16x8 pack8(const fx4 lo, const fx4 hi) {
    bf16x8 o;
    o[0] = (bf16_t)lo[0]; o[1] = (bf16_t)lo[1]; o[2] = (bf16_t)lo[2]; o[3] = (bf16_t)lo[3];
    o[4] = (bf16_t)hi[0]; o[5] = (bf16_t)hi[1]; o[6] = (bf16_t)hi[2]; o[7] = (bf16_t)hi[3];
    return o;
}

// ---------------- router: softmax over 8, top-2, renormalize, compact per expert ----------------
__global__ void router_kernel(const float* __restrict__ gating, int* __restrict__ counts,
                              int* __restrict__ tok_list, float* __restrict__ w_list) {
    int t = blockIdx.x * blockDim.x + threadIdx.x;
    if (t >= T_TOK) return;
    float l[NEXP];
    float mx = -1e30f;
#pragma unroll
    for (int e = 0; e < NEXP; e++) { l[e] = gating[t * NEXP + e]; mx = fmaxf(mx, l[e]); }
#pragma unroll
    for (int e = 0; e < NEXP; e++) { l[e] = __expf(l[e] - mx); }
    int e0 = 0; float p0 = l[0];
#pragma unroll
    for (int e = 1; e < NEXP; e++) { if (l[e] > p0) { p0 = l[e]; e0 = e; } }
    int e1 = -1; float p1 = -1.0f;
#pragma unroll
    for (int e = 0; e < NEXP; e++) { if (e != e0 && l[e] > p1) { p1 = l[e]; e1 = e; } }
    float inv = 1.0f / (p0 + p1);
    int s0 = atomicAdd(&counts[e0], 1);
    tok_list[e0 * T_TOK + s0] = t; w_list[e0 * T_TOK + s0] = p0 * inv;
    int s1 = atomicAdd(&counts[e1], 1);
    tok_list[e1 * T_TOK + s1] = t; w_list[e1 * T_TOK + s1] = p1 * inv;
}

__global__ void scan_kernel(const int* __restrict__ counts, int* __restrict__ offsets) {
    if (threadIdx.x == 0 && blockIdx.x == 0) {
        int acc = 0;
        for (int e = 0; e < NEXP; e++) { offsets[e] = acc; acc += counts[e]; }
        offsets[NEXP] = acc;
    }
}

// ---------------- x fp32 -> bf16 ----------------
__global__ void cvt_x_kernel(const float* __restrict__ x, bf16_t* __restrict__ xb) {
    int i = blockIdx.x * blockDim.x + threadIdx.x;   // one thread = 8 elements
    const fx4* src = (const fx4*)x;
    fx4 v0 = src[2 * i], v1 = src[2 * i + 1];
    *(bf16x8*)(xb + (size_t)i * 8) = pack8(v0, v1);
}

// ---------------- gate_up GEMM: h = silu(x Wg^T) * (x Wu^T), bf16 out ----------------
// block: 128 M x (64 g + 64 u) N, BK=64. 4 waves (2M x 2N), per wave 64x32 g + 64x32 u.
// grid.x = 4096 per expert: s -> xcd r=s&7, m=(s>>3)&31, y=r+8*(s>>8)  (panel-per-XCD clustering)
__global__ __launch_bounds__(256, 3) void gateup_kernel(
    const bf16_t* __restrict__ xb, const float* __restrict__ gup,
    const int* __restrict__ counts, const int* __restrict__ offsets,
    const int* __restrict__ tok_list, bf16_t* __restrict__ h_buf)
{
    const int e = blockIdx.y;
    const int cnt = counts[e];
    const int s = blockIdx.x;
    const int mbase = ((s >> 3) & 31) * 128;
    if (mbase >= cnt) return;
    const int y = (s & 7) + 8 * (s >> 8);     // 0..127
    const int nbase = y * 64;
    const int off_e = offsets[e];

    __shared__ __align__(16) bf16_t lds_a[128 * 64];
    __shared__ __align__(16) bf16_t lds_w[128 * 64];   // rows 0-63: gate, rows 64-127: up

    const int tid = threadIdx.x;
    const int lane = tid & 63;
    const int w = tid >> 6;
    const int wm = (w >> 1) * 64;
    const int wn = (w & 1) * 32;

    // A tile via global_load_lds: wave w stages slots [(w*4+j)*64 + lane], LDS linear,
    // source column chunk pre-swizzled: LDS[row][c] = X[row][c ^ (row&7)]
    const bf16_t* a_src[4];
    bf16_t* a_dst[4];
#pragma unroll
    for (int j = 0; j < 4; j++) {
        int sidx = (w * 4 + j) * 64 + lane;
        int row = sidx >> 3;
        int cc = (lane & 7) ^ (row & 7);
        int slot = mbase + row;
        int tok = (slot < cnt) ? tok_list[e * T_TOK + slot] : 0;
        a_src[j] = xb + (size_t)tok * DMODEL + cc * 8;
        a_dst[j] = lds_a + (w * 4 + j) * 512;
    }
    // W tile (fp32 -> bf16 in regs): 1024 8-float chunks, 4/thread
    const float* w_src[4];
    int w_st[4];
    const float* gbase = gup + (size_t)e * (2 * DFF) * DMODEL;
#pragma unroll
    for (int t = 0; t < 4; t++) {
        int cid = t * 256 + tid;
        int row = cid >> 3, c = cid & 7;
        int grow = (row < 64) ? (nbase + row) : (DFF + nbase + (row - 64));
        w_src[t] = gbase + (size_t)grow * DMODEL + c * 8;
        w_st[t] = row * 64 + ((c ^ (row & 7)) * 8);
    }

    fx4 accg[4][2] = {};
    fx4 accu[4][2] = {};

    for (int k0 = 0; k0 < DMODEL; k0 += 64) {
#pragma unroll
        for (int j = 0; j < 4; j++) { gload16(a_src[j], a_dst[j]); a_src[j] += 64; }
#pragma unroll
        for (int t = 0; t < 4; t++) {
            fx4 lo = *(const fx4*)(w_src[t]);
            fx4 hi = *(const fx4*)(w_src[t] + 4);
            w_src[t] += 64;
            *(bf16x8*)(&lds_w[w_st[t]]) = pack8(lo, hi);
        }
        __syncthreads();
#pragma unroll
        for (int kp = 0; kp < 2; kp++) {
            const int ke = kp * 4 + (lane >> 4);
            bf16x8 af[4], gf[2], uf[2];
#pragma unroll
            for (int i = 0; i < 4; i++) {
                int row = wm + i * 16 + (lane & 15);
                af[i] = *(const bf16x8*)(&lds_a[row * 64 + ((ke ^ (row & 7)) * 8)]);
            }
#pragma unroll
            for (int n = 0; n < 2; n++) {
                int row = wn + n * 16 + (lane & 15);
                gf[n] = *(const bf16x8*)(&lds_w[row * 64 + ((ke ^ (row & 7)) * 8)]);
                uf[n] = *(const bf16x8*)(&lds_w[(row + 64) * 64 + ((ke ^ (row & 7)) * 8)]);
            }
#pragma unroll
            for (int i = 0; i < 4; i++)
#pragma unroll
                for (int n = 0; n < 2; n++) {
                    accg[i][n] = __builtin_amdgcn_mfma_f32_16x16x32_bf16(af[i], gf[n], accg[i][n], 0, 0, 0);
                    accu[i][n] = __builtin_amdgcn_mfma_f32_16x16x32_bf16(af[i], uf[n], accu[i][n], 0, 0, 0);
                }
        }
        __syncthreads();
    }

    // epilogue: h = silu(g) * u -> bf16
    const int colbase = nbase + wn + (lane & 15);
#pragma unroll
    for (int i = 0; i < 4; i++) {
        int rbase = wm + i * 16 + ((lane >> 4) * 4);
#pragma unroll
        for (int j = 0; j < 4; j++) {
            int slot = mbase + rbase + j;
            if (slot < cnt) {
                size_t hrow = (size_t)(off_e + slot);
#pragma unroll
                for (int n = 0; n < 2; n++) {
                    float g = accg[i][n][j];
                    float u = accu[i][n][j];
                    float hv = g * u / (1.0f + __expf(-g));
                    h_buf[hrow * DFF + colbase + n * 16] = (bf16_t)hv;
                }
            }
        }
    }
}

// ---------------- down GEMM: out[tok] += w * (h Wd^T) ----------------
// block: 128 M x 128 N, BK=64, 4 waves (2x2) each 64x64.
// grid.x = 512 per expert: r=s&7, m=(s>>3)&31, y=r+8*(s>>8) (y in [0,16))
__global__ __launch_bounds__(256, 3) void down_kernel(
    const bf16_t* __restrict__ h_buf, const float* __restrict__ dwn,
    const int* __restrict__ counts, const int* __restrict__ offsets,
    const int* __restrict__ tok_list, const float* __restrict__ w_list,
    float* __restrict__ out)
{
    const int e = blockIdx.y;
    const int cnt = counts[e];
    const int s = blockIdx.x;
    const int mbase = ((s >> 3) & 31) * 128;
    if (mbase >= cnt) return;
    const int y = (s & 7) + 8 * (s >> 8);     // 0..15
    const int nbase = y * 128;
    const int off_e = offsets[e];

    __shared__ __align__(16) bf16_t lds_a[128 * 64];
    __shared__ __align__(16) bf16_t lds_b[128 * 64];

    const int tid = threadIdx.x;
    const int lane = tid & 63;
    const int w = tid >> 6;
    const int wm = (w >> 1) * 64;
    const int wn = (w & 1) * 64;

    const bf16_t* a_src[4];
    bf16_t* a_dst[4];
#pragma unroll
    for (int j = 0; j < 4; j++) {
        int sidx = (w * 4 + j) * 64 + lane;
        int row = sidx >> 3;
        int cc = (lane & 7) ^ (row & 7);
        int hrow = off_e + mbase + row;
        if (hrow > NPAIR - 1) hrow = NPAIR - 1;
        a_src[j] = h_buf + (size_t)hrow * DFF + cc * 8;
        a_dst[j] = lds_a + (w * 4 + j) * 512;
    }
    const float* b_src[4];
    int b_st[4];
    const float* bbase = dwn + (size_t)e * DMODEL * DFF;
#pragma unroll
    for (int t = 0; t < 4; t++) {
        int cid = t * 256 + tid;
        int row = cid >> 3, c = cid & 7;
        b_src[t] = bbase + (size_t)(nbase + row) * DFF + c * 8;
        b_st[t] = row * 64 + ((c ^ (row & 7)) * 8);
    }

    fx4 acc[4][4] = {};

    for (int k0 = 0; k0 < DFF; k0 += 64) {
#pragma unroll
        for (int j = 0; j < 4; j++) { gload16(a_src[j], a_dst[j]); a_src[j] += 64; }
#pragma unroll
        for (int t = 0; t < 4; t++) {
            fx4 lo = *(const fx4*)(b_src[t]);
            fx4 hi = *(const fx4*)(b_src[t] + 4);
            b_src[t] += 64;
            *(bf16x8*)(&lds_b[b_st[t]]) = pack8(lo, hi);
        }
        __syncthreads();
#pragma unroll
        for (int kp = 0; kp < 2; kp++) {
            const int ke = kp * 4 + (lane >> 4);
            bf16x8 af[4], bfr[4];
#pragma unroll
            for (int i = 0; i < 4; i++) {
                int row = wm + i * 16 + (lane & 15);
                af[i] = *(const bf16x8*)(&lds_a[row * 64 + ((ke ^ (row & 7)) * 8)]);
            }
#pragma unroll
            for (int n = 0; n < 4; n++) {
                int row = wn + n * 16 + (lane & 15);
                bfr[n] = *(const bf16x8*)(&lds_b[row * 64 + ((ke ^ (row & 7)) * 8)]);
            }
#pragma unroll
            for (int i = 0; i < 4; i++)
#pragma unroll
                for (int n = 0; n < 4; n++)
                    acc[i][n] = __builtin_amdgcn_mfma_f32_16x16x32_bf16(af[i], bfr[n], acc[i][n], 0, 0, 0);
        }
        __syncthreads();
    }

    const int colbase = nbase + wn + (lane & 15);
#pragma unroll
    for (int i = 0; i < 4; i++) {
        int rbase = wm + i * 16 + ((lane >> 4) * 4);
#pragma unroll
        for (int j = 0; j < 4; j++) {
            int slot = mbase + rbase + j;
            if (slot < cnt) {
                int tok = tok_list[e * T_TOK + slot];
                float wgt = w_list[e * T_TOK + slot];
#pragma unroll
                for (int n = 0; n < 4; n++)
                    atomicAdd(&out[(size_t)tok * DMODEL + colbase + n * 16], wgt * acc[i][n][j]);
            }
        }
    }
}

// ---------------- launch ----------------
extern "C" void kernel_launch(void* const* d_in, const int* in_sizes, int n_in,
                              void* d_out, int out_size, void* d_ws, size_t ws_size,
                              hipStream_t stream) {
    const float* x      = (const float*)d_in[0];
    const float* gating = (const float*)d_in[1];
    const float* gup    = (const float*)d_in[2];
    const float* dwn    = (const float*)d_in[3];
    float* out = (float*)d_out;

    char* ws = (char*)d_ws;
    int*    counts   = (int*)(ws + 0);          // 8 ints
    int*    offsets  = (int*)(ws + 64);         // 9 ints
    int*    tok_list = (int*)(ws + 128);        // 8*4096 ints  = 128 KB
    float*  w_list   = (float*)(ws + 128 + 131072);             // 128 KB
    bf16_t* xb       = (bf16_t*)(ws + 262400);                  // 16 MB, 256-aligned
    bf16_t* h_buf    = (bf16_t*)(ws + 17039872);                // 134 MB, 256-aligned

    hipMemsetAsync(counts, 0, 64, stream);
    hipMemsetAsync(out, 0, (size_t)out_size * sizeof(float), stream);

    router_kernel<<<dim3(T_TOK / 256), dim3(256), 0, stream>>>(gating, counts, tok_list, w_list);
    scan_kernel<<<dim3(1), dim3(64), 0, stream>>>(counts, offsets);
    cvt_x_kernel<<<dim3(T_TOK * DMODEL / 8 / 256), dim3(256), 0, stream>>>(x, xb);

    // grid.x: (8 xcd) * (32 m-blocks) * (DFF/64/8 = 16 y-per-xcd) = 4096
    gateup_kernel<<<dim3(4096, NEXP), dim3(256), 0, stream>>>(
        xb, gup, counts, offsets, tok_list, h_buf);

    // grid.x: (8 xcd) * (32 m-blocks) * (DMODEL/128/8 = 2 y-per-xcd) = 512
    down_kernel<<<dim3(512, NEXP), dim3(256), 0, stream>>>(
        h_buf, dwn, counts, offsets, tok_list, w_list, out);
}